// Round 8
// baseline (6362.895 us; speedup 1.0000x reference)
//
#include <hip/hip_runtime.h>

typedef unsigned short u16;

#define NB 32          // batch
#define NS 512         // seq
#define NH 768         // hidden
#define NK 4           // heads
#define NBS 16384      // B*S
#define H3 2304        // 3H
#define HH 589824      // 768*768

// ---------------------------------------------------------------------------
// Workspace (f32). Total 11,087,872 B. Same layout as R5-R7.
//  comb   @ 0           9,437,184  f32 [4][768(m)][768(j)] = pw_W @ Ws_W
//  combB  @ 9,437,184      12,288  f32 [4][768]
//  W_ht   @ 9,449,472     393,216  f32 [4][32][768]
//  scores @ 9,842,688     262,144  f32 [4][32][512]
//  q_f32  @ 10,104,832     98,304  f32 [32][768]
//  hT     @ 10,203,136     98,304  f32 [768][32]
//  xT     @ 10,301,440    196,608  f32 [1536][32]
//  sx     @ 10,498,048    294,912  f32 [32][2304]
//  sh     @ 10,792,960    294,912  f32 [32][2304]
// ---------------------------------------------------------------------------

__global__ void prep0_kernel(const float* __restrict__ WsW, const float* __restrict__ pwb,
                             const float* __restrict__ Wsb, float* __restrict__ combB,
                             const float* __restrict__ question,
                             float* __restrict__ q_f32, float* __restrict__ hT)
{
    int bid = blockIdx.x, t = threadIdx.x;
    if (bid < 12) {
        int idx = bid * 256 + t;
        int k = idx / NH, j = idx % NH;
        float acc = Wsb[idx];
        const float* W = WsW + (long)k * HH + j;
        const float* pb = pwb + k * NH;
        for (int m = 0; m < NH; ++m) acc += pb[m] * W[(long)m * NH];
        combB[idx] = acc;
    } else if (bid < 108) {
        int idx = (bid - 12) * 256 + t;
        q_f32[idx] = question[idx];
    } else {
        int idx = (bid - 108) * 256 + t;
        hT[idx] = 0.f;
    }
}

__global__ __launch_bounds__(256) void comb_valu_kernel(
    const float* __restrict__ pwW, const float* __restrict__ WsW,
    float* __restrict__ comb)
{
    __shared__ float AtT[32][68];
    __shared__ float Bt[32][132];
    const int t = threadIdx.x;
    const int m0 = blockIdx.x * 64, j0 = blockIdx.y * 128, k = blockIdx.z;
    const float* A = pwW + (long)k * HH;
    const float* B = WsW + (long)k * HH;
    const int r4 = (t >> 4) * 4, c8 = (t & 15) * 8;
    float acc[4][8];
    #pragma unroll
    for (int rr = 0; rr < 4; ++rr)
        #pragma unroll
        for (int cc = 0; cc < 8; ++cc) acc[rr][cc] = 0.f;

    for (int h0 = 0; h0 < NH; h0 += 32) {
        #pragma unroll
        for (int p = 0; p < 8; ++p) {
            int idx = p * 256 + t;
            int r = idx >> 5, hh = idx & 31;
            AtT[hh][r] = A[(long)(m0 + r) * NH + h0 + hh];
        }
        #pragma unroll
        for (int p = 0; p < 16; ++p) {
            int idx = p * 256 + t;
            int hh = idx >> 7, c = idx & 127;
            Bt[hh][c] = B[(long)(h0 + hh) * NH + j0 + c];
        }
        __syncthreads();
        for (int hh = 0; hh < 32; ++hh) {
            float4 av  = *(const float4*)&AtT[hh][r4];
            float4 bv0 = *(const float4*)&Bt[hh][c8];
            float4 bv1 = *(const float4*)&Bt[hh][c8 + 4];
            float a[4] = {av.x, av.y, av.z, av.w};
            float bb[8] = {bv0.x, bv0.y, bv0.z, bv0.w, bv1.x, bv1.y, bv1.z, bv1.w};
            #pragma unroll
            for (int rr = 0; rr < 4; ++rr)
                #pragma unroll
                for (int cc = 0; cc < 8; ++cc) acc[rr][cc] += a[rr] * bb[cc];
        }
        __syncthreads();
    }
    float* C = comb + (long)k * HH;
    #pragma unroll
    for (int rr = 0; rr < 4; ++rr)
        #pragma unroll
        for (int cc = 0; cc < 8; ++cc)
            C[(long)(m0 + r4 + rr) * NH + j0 + c8 + cc] = acc[rr][cc];
}

__global__ void sinit_kernel(const float* __restrict__ Web, float* __restrict__ scores)
{
    int idx = blockIdx.x * 256 + threadIdx.x;
    scores[idx] = Web[idx >> 14];
}

__global__ void wht_kernel(const float* __restrict__ q, const float* __restrict__ WtW,
                           const float* __restrict__ Wtb, float* __restrict__ W_ht)
{
    int bid = blockIdx.x;
    int k = bid / 96, rem = bid % 96, b = rem / 3, jt = rem % 3;
    int j = jt * 256 + threadIdx.x;
    const float* W = WtW + (long)k * HH + j;
    const float* qb = q + b * NH;
    float acc = Wtb[k*NH + j];
    for (int h = 0; h < NH; ++h) acc += qb[h] * W[(long)h * NH];
    W_ht[(k*NB + b) * NH + j] = acc;
}

__global__ __launch_bounds__(256) void fused_scores_valu(
    const float* __restrict__ text, const float* __restrict__ comb,
    const float* __restrict__ combB, const float* __restrict__ W_ht,
    const float* __restrict__ WeW, float* __restrict__ scores)
{
    __shared__ float AtT[32][68];
    __shared__ float Bt[32][132];
    __shared__ float wht_s[128];
    __shared__ float we_s[128];
    __shared__ float sred[64];
    const int t = threadIdx.x;
    const int row0 = blockIdx.x * 64;
    const int j0 = blockIdx.y * 128, k = blockIdx.z;
    const int b = row0 >> 9, s0 = row0 & 511;
    const float* B = comb + (long)k * HH;
    const int r4 = (t >> 4) * 4, c8 = (t & 15) * 8;

    if (t < 128) {
        wht_s[t] = W_ht[((k << 5) + b) * NH + j0 + t] + combB[k * NH + j0 + t];
        we_s[t]  = WeW[k * NH + j0 + t];
    }
    if (t < 64) sred[t] = 0.f;

    float acc[4][8];
    #pragma unroll
    for (int rr = 0; rr < 4; ++rr)
        #pragma unroll
        for (int cc = 0; cc < 8; ++cc) acc[rr][cc] = 0.f;

    for (int h0 = 0; h0 < NH; h0 += 32) {
        #pragma unroll
        for (int p = 0; p < 8; ++p) {
            int idx = p * 256 + t;
            int r = idx >> 5, hh = idx & 31;
            AtT[hh][r] = text[(long)(row0 + r) * NH + h0 + hh];
        }
        #pragma unroll
        for (int p = 0; p < 16; ++p) {
            int idx = p * 256 + t;
            int hh = idx >> 7, c = idx & 127;
            Bt[hh][c] = B[(long)(h0 + hh) * NH + j0 + c];
        }
        __syncthreads();
        for (int hh = 0; hh < 32; ++hh) {
            float4 av  = *(const float4*)&AtT[hh][r4];
            float4 bv0 = *(const float4*)&Bt[hh][c8];
            float4 bv1 = *(const float4*)&Bt[hh][c8 + 4];
            float a[4] = {av.x, av.y, av.z, av.w};
            float bb[8] = {bv0.x, bv0.y, bv0.z, bv0.w, bv1.x, bv1.y, bv1.z, bv1.w};
            #pragma unroll
            for (int rr = 0; rr < 4; ++rr)
                #pragma unroll
                for (int cc = 0; cc < 8; ++cc) acc[rr][cc] += a[rr] * bb[cc];
        }
        __syncthreads();
    }
    float part[4] = {0.f, 0.f, 0.f, 0.f};
    #pragma unroll
    for (int rr = 0; rr < 4; ++rr)
        #pragma unroll
        for (int cc = 0; cc < 8; ++cc)
            part[rr] += tanhf(acc[rr][cc] + wht_s[c8 + cc]) * we_s[c8 + cc];
    #pragma unroll
    for (int rr = 0; rr < 4; ++rr)
        atomicAdd(&sred[r4 + rr], part[rr]);
    __syncthreads();
    if (t < 64)
        atomicAdd(&scores[(((k << 5) + b) << 9) + s0 + t], sred[t]);
}

// K5: softmax + alpha_linear + scale + argmax + prob(hop0, f32 out) + xT. grid 32.
__global__ void softmax_kernel(const float* __restrict__ scores,
                               const float* __restrict__ headw_W, const float* __restrict__ headw_b,
                               const float* __restrict__ text,
                               const float* __restrict__ q_f32,
                               float* __restrict__ xT, float* __restrict__ out_prob, int hop)
{
    __shared__ float sc[NK][NS];
    __shared__ float red[256];
    __shared__ float rv[256];
    __shared__ int   ri[256];
    int b = blockIdx.x, t = threadIdx.x;
    for (int i = t; i < NK * NS; i += 256) {
        int k = i >> 9, s = i & 511;
        sc[k][s] = scores[((k*NB + b) << 9) + s];
    }
    __syncthreads();
    float fac[NK];
    for (int k = 0; k < NK; ++k) {
        float v0 = sc[k][t], v1 = sc[k][t + 256];
        red[t] = fmaxf(v0, v1);
        __syncthreads();
        for (int o = 128; o > 0; o >>= 1) { if (t < o) red[t] = fmaxf(red[t], red[t + o]); __syncthreads(); }
        float mx = red[0];
        __syncthreads();
        float e0 = expf(v0 - mx), e1 = expf(v1 - mx);
        sc[k][t] = e0; sc[k][t + 256] = e1;
        red[t] = e0 + e1;
        __syncthreads();
        for (int o = 128; o > 0; o >>= 1) { if (t < o) red[t] += red[t + o]; __syncthreads(); }
        fac[k] = headw_W[k] / red[0];
        __syncthreads();
    }
    float hwb = headw_b[0];
    float a0 = hwb, a1 = hwb;
    for (int k = 0; k < NK; ++k) { a0 += sc[k][t] * fac[k]; a1 += sc[k][t + 256] * fac[k]; }
    red[t] = a0*a0 + a1*a1;
    float bv; int bi;
    if (a0 >= a1) { bv = a0; bi = t; } else { bv = a1; bi = t + 256; }
    rv[t] = bv; ri[t] = bi;
    __syncthreads();
    for (int o = 128; o > 0; o >>= 1) {
        if (t < o) {
            red[t] += red[t + o];
            if (rv[t + o] > rv[t] || (rv[t + o] == rv[t] && ri[t + o] < ri[t])) { rv[t] = rv[t + o]; ri[t] = ri[t + o]; }
        }
        __syncthreads();
    }
    float scale = sqrtf(red[0]);
    int idx = ri[0];
    if (hop == 0) {
        out_prob[(b << 9) + t]       = a0 / scale;
        out_prob[(b << 9) + t + 256] = a1 / scale;
    }
    const float* trow = text + (long)(b * NS + idx) * NH;
    for (int i = t; i < NH; i += 256) {
        xT[i * NB + b]        = q_f32[b*NH + i];
        xT[(NH + i) * NB + b] = trow[i];
    }
}

// DIAG: only fires if scores spread A > 4 (saturation). Writes a bf16-exact f32
// V = 2^(5+cA)*(1+cC/16+cD/64) to float slot 0 — visible under f32 OR bf16 read.
__global__ void diag_kernel(const float* __restrict__ text, const float* __restrict__ comb,
                            const float* __restrict__ scores, float* __restrict__ outp)
{
    __shared__ float red[256];
    int t = threadIdx.x;
    float s00 = scores[0];
    float a = fmaxf(fabsf(scores[t] - s00), fabsf(scores[t + 256] - s00));
    red[t] = a; __syncthreads();
    for (int o = 128; o > 0; o >>= 1) { if (t < o) red[t] = fmaxf(red[t], red[t + o]); __syncthreads(); }
    float A = red[0]; __syncthreads();
    float c = 0.f;
    for (int m = 0; m < 256; ++m) c = fmaxf(c, fabsf(comb[(long)m * NH + t]));
    red[t] = c; __syncthreads();
    for (int o = 128; o > 0; o >>= 1) { if (t < o) red[t] = fmaxf(red[t], red[t + o]); __syncthreads(); }
    float C = red[0]; __syncthreads();
    float d = 0.f;
    for (int i = t; i < 4096; i += 256) d = fmaxf(d, fabsf(text[i]));
    red[t] = d; __syncthreads();
    for (int o = 128; o > 0; o >>= 1) { if (t < o) red[t] = fmaxf(red[t], red[t + o]); __syncthreads(); }
    float Dv = red[0];
    if (t == 0 && A > 4.0f) {
        int cA = (int)floorf(log2f(A)) - 2;
        cA = (cA < 0) ? 0 : ((cA > 7) ? 7 : cA);
        int cC = (C > 0.f) ? (int)floorf(log2f(C)) + 7 : 0;
        cC = (cC < 0) ? 0 : ((cC > 9) ? 9 : cC);
        int cD = (Dv > 0.f) ? (int)floorf(log2f(Dv)) + 2 : 0;
        cD = (cD < 0) ? 0 : ((cD > 7) ? 7 : cD);
        float V = ldexpf(1.f + (float)cC / 16.f + (float)cD / 64.f, 5 + cA);
        outp[0] = V;
    }
}

__global__ __launch_bounds__(256) void gru_mm_kernel(
    const float* __restrict__ Wih, const float* __restrict__ Whh,
    const float* __restrict__ xT, const float* __restrict__ hT,
    float* __restrict__ sx, float* __restrict__ sh)
{
    __shared__ float xs[256 * 32];
    int t = threadIdx.x;
    int j = blockIdx.x * 256 + t;
    float acc[NB];
    #pragma unroll
    for (int b = 0; b < NB; ++b) acc[b] = 0.f;
    for (int c = 0; c < 6; ++c) {
        for (int idx = t; idx < 8192; idx += 256) xs[idx] = xT[c * 8192 + idx];
        __syncthreads();
        for (int ii = 0; ii < 256; ++ii) {
            float w = Wih[(long)(c * 256 + ii) * H3 + j];
            #pragma unroll
            for (int b = 0; b < NB; ++b) acc[b] += xs[ii * 32 + b] * w;
        }
        __syncthreads();
    }
    for (int b = 0; b < NB; ++b) sx[b * H3 + j] = acc[b];
    #pragma unroll
    for (int b = 0; b < NB; ++b) acc[b] = 0.f;
    for (int c = 0; c < 3; ++c) {
        for (int idx = t; idx < 8192; idx += 256) xs[idx] = hT[c * 8192 + idx];
        __syncthreads();
        for (int ii = 0; ii < 256; ++ii) {
            float w = Whh[(long)(c * 256 + ii) * H3 + j];
            #pragma unroll
            for (int b = 0; b < NB; ++b) acc[b] += xs[ii * 32 + b] * w;
        }
        __syncthreads();
    }
    for (int b = 0; b < NB; ++b) sh[b * H3 + j] = acc[b];
}

// K7: gates -> h update (f32 out). grid 96.
__global__ void gate_kernel(const float* __restrict__ sx, const float* __restrict__ sh,
                            const float* __restrict__ bih, const float* __restrict__ bhh,
                            float* __restrict__ hT, float* __restrict__ q_f32,
                            float* __restrict__ out_h, int hop)
{
    int gid = blockIdx.x * 256 + threadIdx.x;
    int b = gid / NH, j = gid % NH;
    float xr = bih[j]        + sx[b*H3 + j];
    float xz = bih[NH + j]   + sx[b*H3 + NH + j];
    float xn = bih[1536 + j] + sx[b*H3 + 1536 + j];
    float hr = bhh[j]        + sh[b*H3 + j];
    float hz = bhh[NH + j]   + sh[b*H3 + NH + j];
    float hn = bhh[1536 + j] + sh[b*H3 + 1536 + j];
    float r = 1.f / (1.f + expf(-(xr + hr)));
    float z = 1.f / (1.f + expf(-(xz + hz)));
    float n = tanhf(xn + r * hn);
    float hp = hT[j * NB + b];
    float hnew = (1.f - z) * n + z * hp;
    hT[j * NB + b] = hnew;
    q_f32[gid] = hnew;
    out_h[(long)(b * 3 + hop) * NH + j] = hnew;
}

// ---------------------------------------------------------------------------
extern "C" void kernel_launch(void* const* d_in, const int* in_sizes, int n_in,
                              void* d_out, int out_size, void* d_ws, size_t ws_size,
                              hipStream_t stream)
{
    const float* question = (const float*)d_in[0];
    const float* text     = (const float*)d_in[1];
    const float* pw_W     = (const float*)d_in[2];
    const float* pw_b     = (const float*)d_in[3];
    const float* Ws_W     = (const float*)d_in[4];
    const float* Ws_b     = (const float*)d_in[5];
    const float* Wt_W     = (const float*)d_in[6];
    const float* Wt_b     = (const float*)d_in[7];
    const float* We_W     = (const float*)d_in[8];
    const float* We_b     = (const float*)d_in[9];
    const float* headw_W  = (const float*)d_in[10];
    const float* headw_b  = (const float*)d_in[11];
    const float* Wih      = (const float*)d_in[12];
    const float* Whh      = (const float*)d_in[13];
    const float* bih      = (const float*)d_in[14];
    const float* bhh      = (const float*)d_in[15];

    char* ws = (char*)d_ws;
    float* comb   = (float*)(ws + 0);
    float* combB  = (float*)(ws + 9437184);
    float* W_ht   = (float*)(ws + 9449472);
    float* scores = (float*)(ws + 9842688);
    float* q_f32  = (float*)(ws + 10104832);
    float* hT     = (float*)(ws + 10203136);
    float* xT     = (float*)(ws + 10301440);
    float* sx     = (float*)(ws + 10498048);
    float* sh     = (float*)(ws + 10792960);

    float* out_prob = (float*)d_out;
    float* out_h    = (float*)d_out + NB * NS;

    prep0_kernel<<<204, 256, 0, stream>>>(Ws_W, pw_b, Ws_b, combB, question, q_f32, hT);
    comb_valu_kernel<<<dim3(12, 6, 4), 256, 0, stream>>>(pw_W, Ws_W, comb);

    for (int hop = 0; hop < 3; ++hop) {
        wht_kernel<<<384, 256, 0, stream>>>(q_f32, Wt_W, Wt_b, W_ht);
        sinit_kernel<<<256, 256, 0, stream>>>(We_b, scores);
        fused_scores_valu<<<dim3(256, 6, 4), 256, 0, stream>>>(
            text, comb, combB, W_ht, We_W, scores);
        softmax_kernel<<<32, 256, 0, stream>>>(scores, headw_W, headw_b, text,
                                               q_f32, xT, out_prob, hop);
        if (hop == 0)
            diag_kernel<<<1, 256, 0, stream>>>(text, comb, scores, out_prob);
        gru_mm_kernel<<<9, 256, 0, stream>>>(Wih, Whh, xT, hT, sx, sh);
        gate_kernel<<<96, 256, 0, stream>>>(sx, sh, bih, bhh, hT, q_f32, out_h, hop);
    }
}

// Round 9
// 1847.747 us; speedup vs baseline: 3.4436x; 3.4436x over previous
//
#include <hip/hip_runtime.h>

typedef unsigned short u16;
typedef __bf16 bf16x8 __attribute__((ext_vector_type(8)));
typedef float f32x4 __attribute__((ext_vector_type(4)));

#define NB 32          // batch
#define NS 512         // seq
#define NH 768         // hidden
#define NK 4           // heads
#define NBS 16384      // B*S
#define H3 2304        // 3H
#define HH 589824      // 768*768

__device__ inline float bf2f(u16 u) {
    unsigned x = ((unsigned)u) << 16;
    return __builtin_bit_cast(float, x);
}
__device__ inline u16 f2bf(float f) {
    unsigned u = __builtin_bit_cast(unsigned, f);
    u += 0x7fffu + ((u >> 16) & 1u);
    return (u16)(u >> 16);
}
// async global->LDS, 16B/lane; LDS dst = wave-uniform base + lane*16 (m97 recipe).
__device__ inline void gld16(const u16* g, u16* l) {
    __builtin_amdgcn_global_load_lds(
        (const __attribute__((address_space(1))) unsigned int*)g,
        (__attribute__((address_space(3))) unsigned int*)l, 16, 0, 0);
}

// ---------------------------------------------------------------------------
// Workspace layout (bytes):
//  comb    @ 0           9,437,184  f32 [4][768(h)][768(j)] = pw_W @ Ws_W
//  combB   @ 9,437,184      12,288  f32 [4][768]
//  W_ht    @ 9,449,472     393,216  f32 [4][32][768]
//  scores  @ 9,842,688     262,144  f32 [4][32][512]
//  q_f32   @ 10,104,832     98,304  f32 [32][768]
//  hT      @ 10,203,136     98,304  f32 [768][32]
//  xT      @ 10,301,440    196,608  f32 [1536][32]
//  sx      @ 10,498,048    294,912  f32 [32][2304]
//  sh      @ 10,792,960    294,912  f32 [32][2304]     -> base end 11,087,872
//  combTH  @ 11,087,872   4,718,592 bf16 [4][j][h] hi   -> 15,806,464
//  combTL  @ 15,806,464   4,718,592 bf16 [4][j][h] lo   -> 20,525,056  TIER1
//  textH   @ 20,525,056  25,165,824 bf16 [bs][h] hi     -> 45,690,880
//  textL   @ 45,690,880  25,165,824 bf16 [bs][h] lo     -> 70,856,704  TIER2
// ---------------------------------------------------------------------------

__global__ void prep0_kernel(const float* __restrict__ WsW, const float* __restrict__ pwb,
                             const float* __restrict__ Wsb, float* __restrict__ combB,
                             const float* __restrict__ question,
                             float* __restrict__ q_f32, float* __restrict__ hT)
{
    int bid = blockIdx.x, t = threadIdx.x;
    if (bid < 12) {
        int idx = bid * 256 + t;
        int k = idx / NH, j = idx % NH;
        float acc = Wsb[idx];
        const float* W = WsW + (long)k * HH + j;
        const float* pb = pwb + k * NH;
        for (int m = 0; m < NH; ++m) acc += pb[m] * W[(long)m * NH];
        combB[idx] = acc;
    } else if (bid < 108) {
        int idx = (bid - 12) * 256 + t;
        q_f32[idx] = question[idx];
    } else {
        int idx = (bid - 108) * 256 + t;
        hT[idx] = 0.f;
    }
}

// comb[k][h][j] = sum_m pw_W[k][h][m] * Ws_W[k][m][j]  (f32 VALU, one-time, small)
__global__ __launch_bounds__(256) void comb_valu_kernel(
    const float* __restrict__ pwW, const float* __restrict__ WsW,
    float* __restrict__ comb)
{
    __shared__ float AtT[32][68];
    __shared__ float Bt[32][132];
    const int t = threadIdx.x;
    const int m0 = blockIdx.x * 64, j0 = blockIdx.y * 128, k = blockIdx.z;
    const float* A = pwW + (long)k * HH;
    const float* B = WsW + (long)k * HH;
    const int r4 = (t >> 4) * 4, c8 = (t & 15) * 8;
    float acc[4][8];
    #pragma unroll
    for (int rr = 0; rr < 4; ++rr)
        #pragma unroll
        for (int cc = 0; cc < 8; ++cc) acc[rr][cc] = 0.f;

    for (int h0 = 0; h0 < NH; h0 += 32) {
        #pragma unroll
        for (int p = 0; p < 8; ++p) {
            int idx = p * 256 + t;
            int r = idx >> 5, hh = idx & 31;
            AtT[hh][r] = A[(long)(m0 + r) * NH + h0 + hh];
        }
        #pragma unroll
        for (int p = 0; p < 16; ++p) {
            int idx = p * 256 + t;
            int hh = idx >> 7, c = idx & 127;
            Bt[hh][c] = B[(long)(h0 + hh) * NH + j0 + c];
        }
        __syncthreads();
        for (int hh = 0; hh < 32; ++hh) {
            float4 av  = *(const float4*)&AtT[hh][r4];
            float4 bv0 = *(const float4*)&Bt[hh][c8];
            float4 bv1 = *(const float4*)&Bt[hh][c8 + 4];
            float a[4] = {av.x, av.y, av.z, av.w};
            float bb[8] = {bv0.x, bv0.y, bv0.z, bv0.w, bv1.x, bv1.y, bv1.z, bv1.w};
            #pragma unroll
            for (int rr = 0; rr < 4; ++rr)
                #pragma unroll
                for (int cc = 0; cc < 8; ++cc) acc[rr][cc] += a[rr] * bb[cc];
        }
        __syncthreads();
    }
    float* C = comb + (long)k * HH;
    #pragma unroll
    for (int rr = 0; rr < 4; ++rr)
        #pragma unroll
        for (int cc = 0; cc < 8; ++cc)
            C[(long)(m0 + r4 + rr) * NH + j0 + c8 + cc] = acc[rr][cc];
}

// TIER>=1: transpose+split comb -> combTH/combTL in [k][j][h]. grid (576,1,4)?
// use blocks: 4 k * 576 tiles = 2304, 256 thr (32x8), 32x32 f32 tiles.
__global__ void split_combT_kernel(const float* __restrict__ comb,
                                   u16* __restrict__ combTH, u16* __restrict__ combTL)
{
    __shared__ float tile[32][33];
    int bid = blockIdx.x, t = threadIdx.x;
    int k = bid / 576, rem = bid % 576, tr = rem / 24, tc = rem % 24;  // tr: h-tile, tc: j-tile
    const float* src = comb + (long)k * HH;
    long dbase = (long)k * HH;
    int tx = t & 31, ty = t >> 5;
    #pragma unroll
    for (int i = 0; i < 4; ++i)
        tile[tx][ty + i*8] = src[(long)(tr*32 + ty + i*8) * NH + tc*32 + tx];
    __syncthreads();
    #pragma unroll
    for (int i = 0; i < 4; ++i) {
        float v = tile[ty + i*8][tx];
        u16 hv = f2bf(v);
        u16 lv = f2bf(v - bf2f(hv));
        long o = dbase + (long)(tc*32 + ty + i*8) * NH + tr*32 + tx;
        combTH[o] = hv;
        combTL[o] = lv;
    }
}

// TIER2: split text f32 -> textH/textL. grid 12288, one float4/thread.
__global__ void split_text_kernel(const float* __restrict__ text,
                                  u16* __restrict__ textH, u16* __restrict__ textL)
{
    long base = (long)blockIdx.x * 1024 + threadIdx.x * 4;
    float4 v = *(const float4*)(text + base);
    ushort4 hv, lv;
    hv.x = f2bf(v.x); lv.x = f2bf(v.x - bf2f(hv.x));
    hv.y = f2bf(v.y); lv.y = f2bf(v.y - bf2f(hv.y));
    hv.z = f2bf(v.z); lv.z = f2bf(v.z - bf2f(hv.z));
    hv.w = f2bf(v.w); lv.w = f2bf(v.w - bf2f(hv.w));
    *(ushort4*)(textH + base) = hv;
    *(ushort4*)(textL + base) = lv;
}

__global__ void sinit_kernel(const float* __restrict__ Web, float* __restrict__ scores)
{
    int idx = blockIdx.x * 256 + threadIdx.x;
    scores[idx] = Web[idx >> 14];
}

__global__ void wht_kernel(const float* __restrict__ q, const float* __restrict__ WtW,
                           const float* __restrict__ Wtb, float* __restrict__ W_ht)
{
    int bid = blockIdx.x;
    int k = bid / 96, rem = bid % 96, b = rem / 3, jt = rem % 3;
    int j = jt * 256 + threadIdx.x;
    const float* W = WtW + (long)k * HH + j;
    const float* qb = q + b * NH;
    float acc = Wtb[k*NH + j];
    for (int h = 0; h < NH; ++h) acc += qb[h] * W[(long)h * NH];
    W_ht[(k*NB + b) * NH + j] = acc;
}

// ---------------------------------------------------------------------------
// MFMA split-bf16 fused scores: W_hs-tile GEMM (3 MFMAs: hi*hi+hi*lo+lo*hi,
// fp32-grade precision) + tanh*We reduce epilogue -> atomicAdd scores.
// AM=1: A from pre-split textH/L (gld16). AM=0: A staged+split in-kernel from f32.
// 128x128 tile, BK=32, grid (128, 6, 4). scores pre-init to We_b.
// ---------------------------------------------------------------------------
template <int AM>
__global__ __launch_bounds__(256) void fused_scores_mfma(
    const float* __restrict__ textf,
    const u16* __restrict__ textH, const u16* __restrict__ textL,
    const u16* __restrict__ combTH, const u16* __restrict__ combTL,
    const float* __restrict__ combB, const float* __restrict__ W_ht,
    const float* __restrict__ WeW, float* __restrict__ scores)
{
    __shared__ __align__(16) u16 AsH[128 * 32];
    __shared__ __align__(16) u16 AsL[128 * 32];
    __shared__ __align__(16) u16 BsH[128 * 32];
    __shared__ __align__(16) u16 BsL[128 * 32];
    __shared__ float wht_s[128];
    __shared__ float we_s[128];
    __shared__ float sred[128];
    const int t = threadIdx.x;
    const int wave = t >> 6, lane = t & 63;
    const int k = blockIdx.z;
    const long m0 = (long)blockIdx.x * 128;
    const int n0 = blockIdx.y * 128;
    const int b = (int)(m0 >> 9), srow = (int)(m0 & 511);
    const u16* BH = combTH + (long)k * HH;
    const u16* BL = combTL + (long)k * HH;

    if (t < 128) {
        wht_s[t] = W_ht[((k << 5) + b) * NH + n0 + t] + combB[k * NH + n0 + t];
        we_s[t]  = WeW[k * NH + n0 + t];
        sred[t]  = 0.f;
    }

    const int r = t >> 2, ch = t & 3;
    const int wm = (wave & 1) * 64, wn = (wave >> 1) * 64;
    const int fr = lane & 15, fq = lane >> 4;

    f32x4 acc[4][4];
    #pragma unroll
    for (int i = 0; i < 4; ++i)
        #pragma unroll
        for (int j = 0; j < 4; ++j) acc[i][j] = (f32x4){0.f, 0.f, 0.f, 0.f};

    for (int h0 = 0; h0 < NH; h0 += 32) {
        if (AM) {
            gld16(textH + (m0 + r)      * NH + h0 + ch*8, AsH + t*8);
            gld16(textH + (m0 + 64 + r) * NH + h0 + ch*8, AsH + 2048 + t*8);
            gld16(textL + (m0 + r)      * NH + h0 + ch*8, AsL + t*8);
            gld16(textL + (m0 + 64 + r) * NH + h0 + ch*8, AsL + 2048 + t*8);
        } else {
            #pragma unroll
            for (int p = 0; p < 4; ++p) {
                int task = p * 256 + t;
                int row = task >> 3, g = task & 7;
                float4 v = *(const float4*)(textf + (m0 + row) * NH + h0 + g*4);
                ushort4 hv, lv;
                hv.x = f2bf(v.x); lv.x = f2bf(v.x - bf2f(hv.x));
                hv.y = f2bf(v.y); lv.y = f2bf(v.y - bf2f(hv.y));
                hv.z = f2bf(v.z); lv.z = f2bf(v.z - bf2f(hv.z));
                hv.w = f2bf(v.w); lv.w = f2bf(v.w - bf2f(hv.w));
                *(ushort4*)(AsH + row * 32 + g*4) = hv;
                *(ushort4*)(AsL + row * 32 + g*4) = lv;
            }
        }
        gld16(BH + (long)(n0 + r)      * NH + h0 + ch*8, BsH + t*8);
        gld16(BH + (long)(n0 + 64 + r) * NH + h0 + ch*8, BsH + 2048 + t*8);
        gld16(BL + (long)(n0 + r)      * NH + h0 + ch*8, BsL + t*8);
        gld16(BL + (long)(n0 + 64 + r) * NH + h0 + ch*8, BsL + 2048 + t*8);
        __syncthreads();
        bf16x8 afH[4], afL[4], bfH[4], bfL[4];
        #pragma unroll
        for (int i = 0; i < 4; ++i) {
            afH[i] = *(const bf16x8*)(AsH + (wm + i*16 + fr)*32 + fq*8);
            afL[i] = *(const bf16x8*)(AsL + (wm + i*16 + fr)*32 + fq*8);
            bfH[i] = *(const bf16x8*)(BsH + (wn + i*16 + fr)*32 + fq*8);
            bfL[i] = *(const bf16x8*)(BsL + (wn + i*16 + fr)*32 + fq*8);
        }
        #pragma unroll
        for (int i = 0; i < 4; ++i)
            #pragma unroll
            for (int j = 0; j < 4; ++j) {
                acc[i][j] = __builtin_amdgcn_mfma_f32_16x16x32_bf16(afH[i], bfH[j], acc[i][j], 0, 0, 0);
                acc[i][j] = __builtin_amdgcn_mfma_f32_16x16x32_bf16(afH[i], bfL[j], acc[i][j], 0, 0, 0);
                acc[i][j] = __builtin_amdgcn_mfma_f32_16x16x32_bf16(afL[i], bfH[j], acc[i][j], 0, 0, 0);
            }
        __syncthreads();
    }
    // epilogue: row m (C/D: col=lane&15, row=fq*4+reg), reduce over n-slice.
    #pragma unroll
    for (int i = 0; i < 4; ++i) {
        #pragma unroll
        for (int rr = 0; rr < 4; ++rr) {
            int m = wm + i*16 + fq*4 + rr;
            float part = 0.f;
            #pragma unroll
            for (int j = 0; j < 4; ++j) {
                int n = wn + j*16 + fr;
                part += tanhf(acc[i][j][rr] + wht_s[n]) * we_s[n];
            }
            part += __shfl_xor(part, 1);
            part += __shfl_xor(part, 2);
            part += __shfl_xor(part, 4);
            part += __shfl_xor(part, 8);
            if (fr == 0) atomicAdd(&sred[m], part);
        }
    }
    __syncthreads();
    if (t < 128)
        atomicAdd(&scores[(((k << 5) + b) << 9) + srow + t], sred[t]);
}

// TIER0 fallback: proven VALU fused kernel (R8). grid (256, 6, 4).
__global__ __launch_bounds__(256) void fused_scores_valu(
    const float* __restrict__ text, const float* __restrict__ comb,
    const float* __restrict__ combB, const float* __restrict__ W_ht,
    const float* __restrict__ WeW, float* __restrict__ scores)
{
    __shared__ float AtT[32][68];
    __shared__ float Bt[32][132];
    __shared__ float wht_s[128];
    __shared__ float we_s[128];
    __shared__ float sred[64];
    const int t = threadIdx.x;
    const int row0 = blockIdx.x * 64;
    const int j0 = blockIdx.y * 128, k = blockIdx.z;
    const int b = row0 >> 9, s0 = row0 & 511;
    const float* B = comb + (long)k * HH;
    const int r4 = (t >> 4) * 4, c8 = (t & 15) * 8;

    if (t < 128) {
        wht_s[t] = W_ht[((k << 5) + b) * NH + j0 + t] + combB[k * NH + j0 + t];
        we_s[t]  = WeW[k * NH + j0 + t];
    }
    if (t < 64) sred[t] = 0.f;

    float acc[4][8];
    #pragma unroll
    for (int rr = 0; rr < 4; ++rr)
        #pragma unroll
        for (int cc = 0; cc < 8; ++cc) acc[rr][cc] = 0.f;

    for (int h0 = 0; h0 < NH; h0 += 32) {
        #pragma unroll
        for (int p = 0; p < 8; ++p) {
            int idx = p * 256 + t;
            int r = idx >> 5, hh = idx & 31;
            AtT[hh][r] = text[(long)(row0 + r) * NH + h0 + hh];
        }
        #pragma unroll
        for (int p = 0; p < 16; ++p) {
            int idx = p * 256 + t;
            int hh = idx >> 7, c = idx & 127;
            Bt[hh][c] = B[(long)(h0 + hh) * NH + j0 + c];
        }
        __syncthreads();
        for (int hh = 0; hh < 32; ++hh) {
            float4 av  = *(const float4*)&AtT[hh][r4];
            float4 bv0 = *(const float4*)&Bt[hh][c8];
            float4 bv1 = *(const float4*)&Bt[hh][c8 + 4];
            float a[4] = {av.x, av.y, av.z, av.w};
            float bb[8] = {bv0.x, bv0.y, bv0.z, bv0.w, bv1.x, bv1.y, bv1.z, bv1.w};
            #pragma unroll
            for (int rr = 0; rr < 4; ++rr)
                #pragma unroll
                for (int cc = 0; cc < 8; ++cc) acc[rr][cc] += a[rr] * bb[cc];
        }
        __syncthreads();
    }
    float part[4] = {0.f, 0.f, 0.f, 0.f};
    #pragma unroll
    for (int rr = 0; rr < 4; ++rr)
        #pragma unroll
        for (int cc = 0; cc < 8; ++cc)
            part[rr] += tanhf(acc[rr][cc] + wht_s[c8 + cc]) * we_s[c8 + cc];
    #pragma unroll
    for (int rr = 0; rr < 4; ++rr)
        atomicAdd(&sred[r4 + rr], part[rr]);
    __syncthreads();
    if (t < 64)
        atomicAdd(&scores[(((k << 5) + b) << 9) + s0 + t], sred[t]);
}

__global__ void softmax_kernel(const float* __restrict__ scores,
                               const float* __restrict__ headw_W, const float* __restrict__ headw_b,
                               const float* __restrict__ text,
                               const float* __restrict__ q_f32,
                               float* __restrict__ xT, float* __restrict__ out_prob, int hop)
{
    __shared__ float sc[NK][NS];
    __shared__ float red[256];
    __shared__ float rv[256];
    __shared__ int   ri[256];
    int b = blockIdx.x, t = threadIdx.x;
    for (int i = t; i < NK * NS; i += 256) {
        int k = i >> 9, s = i & 511;
        sc[k][s] = scores[((k*NB + b) << 9) + s];
    }
    __syncthreads();
    float fac[NK];
    for (int k = 0; k < NK; ++k) {
        float v0 = sc[k][t], v1 = sc[k][t + 256];
        red[t] = fmaxf(v0, v1);
        __syncthreads();
        for (int o = 128; o > 0; o >>= 1) { if (t < o) red[t] = fmaxf(red[t], red[t + o]); __syncthreads(); }
        float mx = red[0];
        __syncthreads();
        float e0 = expf(v0 - mx), e1 = expf(v1 - mx);
        sc[k][t] = e0; sc[k][t + 256] = e1;
        red[t] = e0 + e1;
        __syncthreads();
        for (int o = 128; o > 0; o >>= 1) { if (t < o) red[t] += red[t + o]; __syncthreads(); }
        fac[k] = headw_W[k] / red[0];
        __syncthreads();
    }
    float hwb = headw_b[0];
    float a0 = hwb, a1 = hwb;
    for (int k = 0; k < NK; ++k) { a0 += sc[k][t] * fac[k]; a1 += sc[k][t + 256] * fac[k]; }
    red[t] = a0*a0 + a1*a1;
    float bv; int bi;
    if (a0 >= a1) { bv = a0; bi = t; } else { bv = a1; bi = t + 256; }
    rv[t] = bv; ri[t] = bi;
    __syncthreads();
    for (int o = 128; o > 0; o >>= 1) {
        if (t < o) {
            red[t] += red[t + o];
            if (rv[t + o] > rv[t] || (rv[t + o] == rv[t] && ri[t + o] < ri[t])) { rv[t] = rv[t + o]; ri[t] = ri[t + o]; }
        }
        __syncthreads();
    }
    float scale = sqrtf(red[0]);
    int idx = ri[0];
    if (hop == 0) {
        out_prob[(b << 9) + t]       = a0 / scale;
        out_prob[(b << 9) + t + 256] = a1 / scale;
    }
    const float* trow = text + (long)(b * NS + idx) * NH;
    for (int i = t; i < NH; i += 256) {
        xT[i * NB + b]        = q_f32[b*NH + i];
        xT[(NH + i) * NB + b] = trow[i];
    }
}

// GRU matvecs v2: grid 36 (64-col j-tiles), 256 thr; thread = (tj, tq), 8 b each.
// Same per-(b,j) accumulation order as v1 -> bitwise-identical results.
__global__ __launch_bounds__(256) void gru_mm2_kernel(
    const float* __restrict__ Wih, const float* __restrict__ Whh,
    const float* __restrict__ xT, const float* __restrict__ hT,
    float* __restrict__ sx, float* __restrict__ sh)
{
    __shared__ float xs[8192];
    int t = threadIdx.x;
    int tj = t & 63, tq = t >> 6;
    int j = blockIdx.x * 64 + tj;
    float acc[8];
    #pragma unroll
    for (int bq = 0; bq < 8; ++bq) acc[bq] = 0.f;
    for (int c = 0; c < 6; ++c) {
        for (int idx = t; idx < 8192; idx += 256) xs[idx] = xT[c * 8192 + idx];
        __syncthreads();
        for (int ii = 0; ii < 256; ++ii) {
            float w = Wih[(long)(c * 256 + ii) * H3 + j];
            #pragma unroll
            for (int bq = 0; bq < 8; ++bq) acc[bq] += xs[ii * 32 + tq * 8 + bq] * w;
        }
        __syncthreads();
    }
    #pragma unroll
    for (int bq = 0; bq < 8; ++bq) sx[(long)(tq * 8 + bq) * H3 + j] = acc[bq];
    #pragma unroll
    for (int bq = 0; bq < 8; ++bq) acc[bq] = 0.f;
    for (int c = 0; c < 3; ++c) {
        for (int idx = t; idx < 8192; idx += 256) xs[idx] = hT[c * 8192 + idx];
        __syncthreads();
        for (int ii = 0; ii < 256; ++ii) {
            float w = Whh[(long)(c * 256 + ii) * H3 + j];
            #pragma unroll
            for (int bq = 0; bq < 8; ++bq) acc[bq] += xs[ii * 32 + tq * 8 + bq] * w;
        }
        __syncthreads();
    }
    #pragma unroll
    for (int bq = 0; bq < 8; ++bq) sh[(long)(tq * 8 + bq) * H3 + j] = acc[bq];
}

__global__ void gate_kernel(const float* __restrict__ sx, const float* __restrict__ sh,
                            const float* __restrict__ bih, const float* __restrict__ bhh,
                            float* __restrict__ hT, float* __restrict__ q_f32,
                            float* __restrict__ out_h, int hop)
{
    int gid = blockIdx.x * 256 + threadIdx.x;
    int b = gid / NH, j = gid % NH;
    float xr = bih[j]        + sx[b*H3 + j];
    float xz = bih[NH + j]   + sx[b*H3 + NH + j];
    float xn = bih[1536 + j] + sx[b*H3 + 1536 + j];
    float hr = bhh[j]        + sh[b*H3 + j];
    float hz = bhh[NH + j]   + sh[b*H3 + NH + j];
    float hn = bhh[1536 + j] + sh[b*H3 + 1536 + j];
    float r = 1.f / (1.f + expf(-(xr + hr)));
    float z = 1.f / (1.f + expf(-(xz + hz)));
    float n = tanhf(xn + r * hn);
    float hp = hT[j * NB + b];
    float hnew = (1.f - z) * n + z * hp;
    hT[j * NB + b] = hnew;
    q_f32[gid] = hnew;
    out_h[(long)(b * 3 + hop) * NH + j] = hnew;
}

// ---------------------------------------------------------------------------
extern "C" void kernel_launch(void* const* d_in, const int* in_sizes, int n_in,
                              void* d_out, int out_size, void* d_ws, size_t ws_size,
                              hipStream_t stream)
{
    const float* question = (const float*)d_in[0];
    const float* text     = (const float*)d_in[1];
    const float* pw_W     = (const float*)d_in[2];
    const float* pw_b     = (const float*)d_in[3];
    const float* Ws_W     = (const float*)d_in[4];
    const float* Ws_b     = (const float*)d_in[5];
    const float* Wt_W     = (const float*)d_in[6];
    const float* Wt_b     = (const float*)d_in[7];
    const float* We_W     = (const float*)d_in[8];
    const float* We_b     = (const float*)d_in[9];
    const float* headw_W  = (const float*)d_in[10];
    const float* headw_b  = (const float*)d_in[11];
    const float* Wih      = (const float*)d_in[12];
    const float* Whh      = (const float*)d_in[13];
    const float* bih      = (const float*)d_in[14];
    const float* bhh      = (const float*)d_in[15];

    char* ws = (char*)d_ws;
    float* comb   = (float*)(ws + 0);
    float* combB  = (float*)(ws + 9437184);
    float* W_ht   = (float*)(ws + 9449472);
    float* scores = (float*)(ws + 9842688);
    float* q_f32  = (float*)(ws + 10104832);
    float* hT     = (float*)(ws + 10203136);
    float* xT     = (float*)(ws + 10301440);
    float* sx     = (float*)(ws + 10498048);
    float* sh     = (float*)(ws + 10792960);
    u16*   combTH = (u16*)  (ws + 11087872);
    u16*   combTL = (u16*)  (ws + 15806464);
    u16*   textH  = (u16*)  (ws + 20525056);
    u16*   textL  = (u16*)  (ws + 45690880);
    const int tier = (ws_size >= (size_t)70856704) ? 2
                   : (ws_size >= (size_t)20525056) ? 1 : 0;

    float* out_prob = (float*)d_out;
    float* out_h    = (float*)d_out + NB * NS;

    prep0_kernel<<<204, 256, 0, stream>>>(Ws_W, pw_b, Ws_b, combB, question, q_f32, hT);
    comb_valu_kernel<<<dim3(12, 6, 4), 256, 0, stream>>>(pw_W, Ws_W, comb);
    if (tier >= 1)
        split_combT_kernel<<<2304, 256, 0, stream>>>(comb, combTH, combTL);
    if (tier == 2)
        split_text_kernel<<<12288, 256, 0, stream>>>(text, textH, textL);

    for (int hop = 0; hop < 3; ++hop) {
        wht_kernel<<<384, 256, 0, stream>>>(q_f32, Wt_W, Wt_b, W_ht);
        sinit_kernel<<<256, 256, 0, stream>>>(We_b, scores);
        if (tier == 2) {
            fused_scores_mfma<1><<<dim3(128, 6, 4), 256, 0, stream>>>(
                text, textH, textL, combTH, combTL, combB, W_ht, We_W, scores);
        } else if (tier == 1) {
            fused_scores_mfma<0><<<dim3(128, 6, 4), 256, 0, stream>>>(
                text, nullptr, nullptr, combTH, combTL, combB, W_ht, We_W, scores);
        } else {
            fused_scores_valu<<<dim3(256, 6, 4), 256, 0, stream>>>(
                text, comb, combB, W_ht, We_W, scores);
        }
        softmax_kernel<<<32, 256, 0, stream>>>(scores, headw_W, headw_b, text,
                                               q_f32, xT, out_prob, hop);
        gru_mm2_kernel<<<36, 256, 0, stream>>>(Wih, Whh, xT, hT, sx, sh);
        gate_kernel<<<96, 256, 0, stream>>>(sx, sh, bih, bhh, hT, q_f32, out_h, hop);
    }
}

// Round 11
// 1235.105 us; speedup vs baseline: 5.1517x; 1.4960x over previous
//
#include <hip/hip_runtime.h>

typedef unsigned short u16;
typedef __bf16 bf16x8 __attribute__((ext_vector_type(8)));
typedef float f32x4 __attribute__((ext_vector_type(4)));

#define NB 32          // batch
#define NS 512         // seq
#define NH 768         // hidden
#define NK 4           // heads
#define NBS 16384      // B*S
#define H3 2304        // 3H
#define HH 589824      // 768*768

__device__ inline float bf2f(u16 u) {
    unsigned x = ((unsigned)u) << 16;
    return __builtin_bit_cast(float, x);
}
__device__ inline u16 f2bf(float f) {
    unsigned u = __builtin_bit_cast(unsigned, f);
    u += 0x7fffu + ((u >> 16) & 1u);
    return (u16)(u >> 16);
}
// async global->LDS, 16B/lane; LDS dst = wave-uniform base + lane*16 (m97 recipe).
__device__ inline void gld16(const u16* g, u16* l) {
    __builtin_amdgcn_global_load_lds(
        (const __attribute__((address_space(1))) unsigned int*)g,
        (__attribute__((address_space(3))) unsigned int*)l, 16, 0, 0);
}

// ---------------------------------------------------------------------------
// Workspace layout (bytes):
//  comb    @ 0           9,437,184  f32 [4][768(h)][768(j)]  (tier 0/1 only)
//  combB   @ 9,437,184      12,288  f32 [4][768]
//  W_ht    @ 9,449,472     393,216  f32 [4][32][768]
//  scores  @ 9,842,688     262,144  f32 [4][32][512]
//  q_f32   @ 10,104,832     98,304  f32 [32][768]
//  hT      @ 10,203,136     98,304  f32 [768][32]
//  xT      @ 10,301,440    196,608  f32 [1536][32]
//  sx      @ 10,498,048    294,912  f32 [32][2304]  (73,728 floats)
//  sh      @ 10,792,960    294,912  f32 [32][2304]  (73,728 floats) -> 11,087,872
//  combTH  @ 11,087,872   4,718,592 bf16 [4][j][h] hi
//  combTL  @ 15,806,464   4,718,592 bf16 [4][j][h] lo   -> 20,525,056  TIER1
//  textH   @ 20,525,056  25,165,824 bf16 [bs][h] hi
//  textL   @ 45,690,880  25,165,824 bf16 [bs][h] lo     -> 70,856,704  TIER2
//  TIER2 prep scratch overlaid on textH region (consumed before split_text):
//   WsTH @ 20,525,056  WsTL @ 25,243,648  pwH @ 29,962,240  pwL @ 34,680,832
// ---------------------------------------------------------------------------

// P: one-time prep (all tiers; tier2 sections gated).
__global__ void prep_kernel(const float* __restrict__ WsW, const float* __restrict__ pwb,
                            const float* __restrict__ Wsb, float* __restrict__ combB,
                            const float* __restrict__ question,
                            float* __restrict__ q_f32, float* __restrict__ hT,
                            const float* __restrict__ pwW,
                            u16* __restrict__ WsTH, u16* __restrict__ WsTL,
                            u16* __restrict__ pwH, u16* __restrict__ pwL, int tier)
{
    int bid = blockIdx.x, t = threadIdx.x;
    if (bid < 48) {
        int idx = bid * 64 + (t >> 2);      // 0..3071
        int ph = t & 3;
        int k = idx / NH, j = idx % NH;
        const float* W = WsW + (long)k * HH + j;
        const float* pb = pwb + k * NH;
        float acc = 0.f;
        #pragma unroll 8
        for (int m = ph * 192; m < ph * 192 + 192; ++m)
            acc += pb[m] * W[(long)m * NH];
        acc += __shfl_xor(acc, 1);
        acc += __shfl_xor(acc, 2);
        if (ph == 0) combB[idx] = acc + Wsb[idx];
    } else if (bid < 144) {
        int idx = (bid - 48) * 256 + t;
        q_f32[idx] = question[idx];
    } else if (bid < 240) {
        int idx = (bid - 144) * 256 + t;
        hT[idx] = 0.f;
    } else if (bid < 2544) {
        if (tier < 2) return;
        __shared__ float tile[32][33];
        int bid2 = bid - 240;
        int k = bid2 / 576, rem = bid2 % 576, tr = rem / 24, tc = rem % 24;
        const float* src = WsW + (long)k * HH;
        long dbase = (long)k * HH;
        int tx = t & 31, ty = t >> 5;
        #pragma unroll
        for (int i = 0; i < 4; ++i)
            tile[tx][ty + i*8] = src[(long)(tr*32 + ty + i*8) * NH + tc*32 + tx];
        __syncthreads();
        #pragma unroll
        for (int i = 0; i < 4; ++i) {
            float v = tile[ty + i*8][tx];
            u16 hv = f2bf(v);
            u16 lv = f2bf(v - bf2f(hv));
            long o = dbase + (long)(tc*32 + ty + i*8) * NH + tr*32 + tx;
            WsTH[o] = hv; WsTL[o] = lv;
        }
    } else {
        if (tier < 2) return;
        long base = (long)(bid - 2544) * 1024 + t * 4;
        float4 v = *(const float4*)(pwW + base);
        ushort4 hv, lv;
        hv.x = f2bf(v.x); lv.x = f2bf(v.x - bf2f(hv.x));
        hv.y = f2bf(v.y); lv.y = f2bf(v.y - bf2f(hv.y));
        hv.z = f2bf(v.z); lv.z = f2bf(v.z - bf2f(hv.z));
        hv.w = f2bf(v.w); lv.w = f2bf(v.w - bf2f(hv.w));
        *(ushort4*)(pwH + base) = hv;
        *(ushort4*)(pwL + base) = lv;
    }
}

// TIER2: combT[k][j][h] = sum_m WsT[k][j][m] * pw[k][h][m], split-bf16 3-MFMA.
__global__ __launch_bounds__(256) void comb_mfma_kernel(
    const u16* __restrict__ WsTH, const u16* __restrict__ WsTL,
    const u16* __restrict__ pwH, const u16* __restrict__ pwL,
    u16* __restrict__ combTH, u16* __restrict__ combTL)
{
    __shared__ __align__(16) u16 AsH[128 * 32];
    __shared__ __align__(16) u16 AsL[128 * 32];
    __shared__ __align__(16) u16 BsH[128 * 32];
    __shared__ __align__(16) u16 BsL[128 * 32];
    const int t = threadIdx.x;
    const int wave = t >> 6, lane = t & 63;
    const int k = blockIdx.z;
    const long m0 = (long)blockIdx.x * 128;   // j-rows
    const int n0 = blockIdx.y * 128;          // h-cols
    const u16* AH = WsTH + (long)k * HH;
    const u16* AL = WsTL + (long)k * HH;
    const u16* BH = pwH + (long)k * HH;
    const u16* BL = pwL + (long)k * HH;

    const int r = t >> 2, ch = t & 3;
    const int wm = (wave & 1) * 64, wn = (wave >> 1) * 64;
    const int fr = lane & 15, fq = lane >> 4;

    f32x4 acc[4][4];
    #pragma unroll
    for (int i = 0; i < 4; ++i)
        #pragma unroll
        for (int j = 0; j < 4; ++j) acc[i][j] = (f32x4){0.f, 0.f, 0.f, 0.f};

    for (int k0 = 0; k0 < NH; k0 += 32) {
        gld16(AH + (m0 + r)      * NH + k0 + ch*8, AsH + t*8);
        gld16(AH + (m0 + 64 + r) * NH + k0 + ch*8, AsH + 2048 + t*8);
        gld16(AL + (m0 + r)      * NH + k0 + ch*8, AsL + t*8);
        gld16(AL + (m0 + 64 + r) * NH + k0 + ch*8, AsL + 2048 + t*8);
        gld16(BH + (long)(n0 + r)      * NH + k0 + ch*8, BsH + t*8);
        gld16(BH + (long)(n0 + 64 + r) * NH + k0 + ch*8, BsH + 2048 + t*8);
        gld16(BL + (long)(n0 + r)      * NH + k0 + ch*8, BsL + t*8);
        gld16(BL + (long)(n0 + 64 + r) * NH + k0 + ch*8, BsL + 2048 + t*8);
        __syncthreads();
        bf16x8 afH[4], afL[4], bfH[4], bfL[4];
        #pragma unroll
        for (int i = 0; i < 4; ++i) {
            afH[i] = *(const bf16x8*)(AsH + (wm + i*16 + fr)*32 + fq*8);
            afL[i] = *(const bf16x8*)(AsL + (wm + i*16 + fr)*32 + fq*8);
            bfH[i] = *(const bf16x8*)(BsH + (wn + i*16 + fr)*32 + fq*8);
            bfL[i] = *(const bf16x8*)(BsL + (wn + i*16 + fr)*32 + fq*8);
        }
        #pragma unroll
        for (int i = 0; i < 4; ++i)
            #pragma unroll
            for (int j = 0; j < 4; ++j) {
                acc[i][j] = __builtin_amdgcn_mfma_f32_16x16x32_bf16(afH[i], bfH[j], acc[i][j], 0, 0, 0);
                acc[i][j] = __builtin_amdgcn_mfma_f32_16x16x32_bf16(afH[i], bfL[j], acc[i][j], 0, 0, 0);
                acc[i][j] = __builtin_amdgcn_mfma_f32_16x16x32_bf16(afL[i], bfH[j], acc[i][j], 0, 0, 0);
            }
        __syncthreads();
    }
    long kb = (long)k * HH;
    #pragma unroll
    for (int i = 0; i < 4; ++i) {
        long m = m0 + wm + i*16 + fq*4;       // j-row
        #pragma unroll
        for (int j = 0; j < 4; ++j) {
            long n = n0 + wn + j*16 + fr;     // h-col
            #pragma unroll
            for (int rr = 0; rr < 4; ++rr) {
                float v = acc[i][j][rr];
                u16 hv = f2bf(v);
                u16 lv = f2bf(v - bf2f(hv));
                combTH[kb + (m + rr) * NH + n] = hv;
                combTL[kb + (m + rr) * NH + n] = lv;
            }
        }
    }
}

// tier 0/1: comb[k][h][j] f32 VALU GEMM (proven R8 kernel).
__global__ __launch_bounds__(256) void comb_valu_kernel(
    const float* __restrict__ pwW, const float* __restrict__ WsW,
    float* __restrict__ comb)
{
    __shared__ float AtT[32][68];
    __shared__ float Bt[32][132];
    const int t = threadIdx.x;
    const int m0 = blockIdx.x * 64, j0 = blockIdx.y * 128, k = blockIdx.z;
    const float* A = pwW + (long)k * HH;
    const float* B = WsW + (long)k * HH;
    const int r4 = (t >> 4) * 4, c8 = (t & 15) * 8;
    float acc[4][8];
    #pragma unroll
    for (int rr = 0; rr < 4; ++rr)
        #pragma unroll
        for (int cc = 0; cc < 8; ++cc) acc[rr][cc] = 0.f;
    for (int h0 = 0; h0 < NH; h0 += 32) {
        #pragma unroll
        for (int p = 0; p < 8; ++p) {
            int idx = p * 256 + t;
            int r = idx >> 5, hh = idx & 31;
            AtT[hh][r] = A[(long)(m0 + r) * NH + h0 + hh];
        }
        #pragma unroll
        for (int p = 0; p < 16; ++p) {
            int idx = p * 256 + t;
            int hh = idx >> 7, c = idx & 127;
            Bt[hh][c] = B[(long)(h0 + hh) * NH + j0 + c];
        }
        __syncthreads();
        for (int hh = 0; hh < 32; ++hh) {
            float4 av  = *(const float4*)&AtT[hh][r4];
            float4 bv0 = *(const float4*)&Bt[hh][c8];
            float4 bv1 = *(const float4*)&Bt[hh][c8 + 4];
            float a[4] = {av.x, av.y, av.z, av.w};
            float bb[8] = {bv0.x, bv0.y, bv0.z, bv0.w, bv1.x, bv1.y, bv1.z, bv1.w};
            #pragma unroll
            for (int rr = 0; rr < 4; ++rr)
                #pragma unroll
                for (int cc = 0; cc < 8; ++cc) acc[rr][cc] += a[rr] * bb[cc];
        }
        __syncthreads();
    }
    float* C = comb + (long)k * HH;
    #pragma unroll
    for (int rr = 0; rr < 4; ++rr)
        #pragma unroll
        for (int cc = 0; cc < 8; ++cc)
            C[(long)(m0 + r4 + rr) * NH + j0 + c8 + cc] = acc[rr][cc];
}

// tier1: transpose+split comb f32 -> combTH/combTL. grid 2304.
__global__ void split_combT_kernel(const float* __restrict__ comb,
                                   u16* __restrict__ combTH, u16* __restrict__ combTL)
{
    __shared__ float tile[32][33];
    int bid = blockIdx.x, t = threadIdx.x;
    int k = bid / 576, rem = bid % 576, tr = rem / 24, tc = rem % 24;
    const float* src = comb + (long)k * HH;
    long dbase = (long)k * HH;
    int tx = t & 31, ty = t >> 5;
    #pragma unroll
    for (int i = 0; i < 4; ++i)
        tile[tx][ty + i*8] = src[(long)(tr*32 + ty + i*8) * NH + tc*32 + tx];
    __syncthreads();
    #pragma unroll
    for (int i = 0; i < 4; ++i) {
        float v = tile[ty + i*8][tx];
        u16 hv = f2bf(v);
        u16 lv = f2bf(v - bf2f(hv));
        long o = dbase + (long)(tc*32 + ty + i*8) * NH + tr*32 + tx;
        combTH[o] = hv; combTL[o] = lv;
    }
}

// TIER2: split text f32 -> textH/textL. grid 12288 (after comb_mfma!).
__global__ void split_text_kernel(const float* __restrict__ text,
                                  u16* __restrict__ textH, u16* __restrict__ textL)
{
    long base = (long)blockIdx.x * 1024 + threadIdx.x * 4;
    float4 v = *(const float4*)(text + base);
    ushort4 hv, lv;
    hv.x = f2bf(v.x); lv.x = f2bf(v.x - bf2f(hv.x));
    hv.y = f2bf(v.y); lv.y = f2bf(v.y - bf2f(hv.y));
    hv.z = f2bf(v.z); lv.z = f2bf(v.z - bf2f(hv.z));
    hv.w = f2bf(v.w); lv.w = f2bf(v.w - bf2f(hv.w));
    *(ushort4*)(textH + base) = hv;
    *(ushort4*)(textL + base) = lv;
}

// Per-hop init: scores=We_b (65,536 f), W_ht=Wt_b (98,304 f), sx/sh=0 (147,456 f).
// grid 1216 = 256 + 384 + 576.
__global__ void init_hop_kernel(const float* __restrict__ Web, float* __restrict__ scores,
                                const float* __restrict__ Wtb, float* __restrict__ W_ht,
                                float* __restrict__ sx, float* __restrict__ sh)
{
    int bid = blockIdx.x, t = threadIdx.x;
    if (bid < 256) {
        int idx = bid * 256 + t;              // 65,536
        scores[idx] = Web[idx >> 14];
    } else if (bid < 640) {
        int idx = (bid - 256) * 256 + t;      // 98,304
        int k = idx / 24576, j = idx % NH;
        W_ht[idx] = Wtb[k * NH + j];
    } else {
        int idx = (bid - 640) * 256 + t;      // 147,456 floats total (NOT bytes!)
        if (idx < 73728) sx[idx] = 0.f;
        else sh[idx - 73728] = 0.f;
    }
}

// W_ht partials: grid 1536 = 4k x 32b x 3jt x 4hg; atomicAdd into W_ht.
__global__ void wht2_kernel(const float* __restrict__ q, const float* __restrict__ WtW,
                            float* __restrict__ W_ht)
{
    int bid = blockIdx.x;
    int k = bid / 384, rem = bid % 384, b = rem / 12, rem2 = rem % 12;
    int jt = rem2 / 4, hg = rem2 % 4;
    int j = jt * 256 + threadIdx.x;
    const float* W = WtW + (long)k * HH + j;
    const float* qb = q + b * NH;
    float acc = 0.f;
    #pragma unroll 8
    for (int h = hg * 192; h < hg * 192 + 192; ++h) acc += qb[h] * W[(long)h * NH];
    atomicAdd(&W_ht[(k*NB + b) * NH + j], acc);
}

// ---------------------------------------------------------------------------
// MFMA split-bf16 fused scores (proven R9). grid (128, 6, 4).
// ---------------------------------------------------------------------------
template <int AM>
__global__ __launch_bounds__(256) void fused_scores_mfma(
    const float* __restrict__ textf,
    const u16* __restrict__ textH, const u16* __restrict__ textL,
    const u16* __restrict__ combTH, const u16* __restrict__ combTL,
    const float* __restrict__ combB, const float* __restrict__ W_ht,
    const float* __restrict__ WeW, float* __restrict__ scores)
{
    __shared__ __align__(16) u16 AsH[128 * 32];
    __shared__ __align__(16) u16 AsL[128 * 32];
    __shared__ __align__(16) u16 BsH[128 * 32];
    __shared__ __align__(16) u16 BsL[128 * 32];
    __shared__ float wht_s[128];
    __shared__ float we_s[128];
    __shared__ float sred[128];
    const int t = threadIdx.x;
    const int wave = t >> 6, lane = t & 63;
    const int k = blockIdx.z;
    const long m0 = (long)blockIdx.x * 128;
    const int n0 = blockIdx.y * 128;
    const int b = (int)(m0 >> 9), srow = (int)(m0 & 511);
    const u16* BH = combTH + (long)k * HH;
    const u16* BL = combTL + (long)k * HH;

    if (t < 128) {
        wht_s[t] = W_ht[((k << 5) + b) * NH + n0 + t] + combB[k * NH + n0 + t];
        we_s[t]  = WeW[k * NH + n0 + t];
        sred[t]  = 0.f;
    }

    const int r = t >> 2, ch = t & 3;
    const int wm = (wave & 1) * 64, wn = (wave >> 1) * 64;
    const int fr = lane & 15, fq = lane >> 4;

    f32x4 acc[4][4];
    #pragma unroll
    for (int i = 0; i < 4; ++i)
        #pragma unroll
        for (int j = 0; j < 4; ++j) acc[i][j] = (f32x4){0.f, 0.f, 0.f, 0.f};

    for (int h0 = 0; h0 < NH; h0 += 32) {
        if (AM) {
            gld16(textH + (m0 + r)      * NH + h0 + ch*8, AsH + t*8);
            gld16(textH + (m0 + 64 + r) * NH + h0 + ch*8, AsH + 2048 + t*8);
            gld16(textL + (m0 + r)      * NH + h0 + ch*8, AsL + t*8);
            gld16(textL + (m0 + 64 + r) * NH + h0 + ch*8, AsL + 2048 + t*8);
        } else {
            #pragma unroll
            for (int p = 0; p < 4; ++p) {
                int task = p * 256 + t;
                int row = task >> 3, g = task & 7;
                float4 v = *(const float4*)(textf + (m0 + row) * NH + h0 + g*4);
                ushort4 hv, lv;
                hv.x = f2bf(v.x); lv.x = f2bf(v.x - bf2f(hv.x));
                hv.y = f2bf(v.y); lv.y = f2bf(v.y - bf2f(hv.y));
                hv.z = f2bf(v.z); lv.z = f2bf(v.z - bf2f(hv.z));
                hv.w = f2bf(v.w); lv.w = f2bf(v.w - bf2f(hv.w));
                *(ushort4*)(AsH + row * 32 + g*4) = hv;
                *(ushort4*)(AsL + row * 32 + g*4) = lv;
            }
        }
        gld16(BH + (long)(n0 + r)      * NH + h0 + ch*8, BsH + t*8);
        gld16(BH + (long)(n0 + 64 + r) * NH + h0 + ch*8, BsH + 2048 + t*8);
        gld16(BL + (long)(n0 + r)      * NH + h0 + ch*8, BsL + t*8);
        gld16(BL + (long)(n0 + 64 + r) * NH + h0 + ch*8, BsL + 2048 + t*8);
        __syncthreads();
        bf16x8 afH[4], afL[4], bfH[4], bfL[4];
        #pragma unroll
        for (int i = 0; i < 4; ++i) {
            afH[i] = *(const bf16x8*)(AsH + (wm + i*16 + fr)*32 + fq*8);
            afL[i] = *(const bf16x8*)(AsL + (wm + i*16 + fr)*32 + fq*8);
            bfH[i] = *(const bf16x8*)(BsH + (wn + i*16 + fr)*32 + fq*8);
            bfL[i] = *(const bf16x8*)(BsL + (wn + i*16 + fr)*32 + fq*8);
        }
        #pragma unroll
        for (int i = 0; i < 4; ++i)
            #pragma unroll
            for (int j = 0; j < 4; ++j) {
                acc[i][j] = __builtin_amdgcn_mfma_f32_16x16x32_bf16(afH[i], bfH[j], acc[i][j], 0, 0, 0);
                acc[i][j] = __builtin_amdgcn_mfma_f32_16x16x32_bf16(afH[i], bfL[j], acc[i][j], 0, 0, 0);
                acc[i][j] = __builtin_amdgcn_mfma_f32_16x16x32_bf16(afL[i], bfH[j], acc[i][j], 0, 0, 0);
            }
        __syncthreads();
    }
    #pragma unroll
    for (int i = 0; i < 4; ++i) {
        #pragma unroll
        for (int rr = 0; rr < 4; ++rr) {
            int m = wm + i*16 + fq*4 + rr;
            float part = 0.f;
            #pragma unroll
            for (int j = 0; j < 4; ++j) {
                int n = wn + j*16 + fr;
                part += tanhf(acc[i][j][rr] + wht_s[n]) * we_s[n];
            }
            part += __shfl_xor(part, 1);
            part += __shfl_xor(part, 2);
            part += __shfl_xor(part, 4);
            part += __shfl_xor(part, 8);
            if (fr == 0) atomicAdd(&sred[m], part);
        }
    }
    __syncthreads();
    if (t < 128)
        atomicAdd(&scores[(((k << 5) + b) << 9) + srow + t], sred[t]);
}

// tier0 fallback (proven R8). grid (256, 6, 4).
__global__ __launch_bounds__(256) void fused_scores_valu(
    const float* __restrict__ text, const float* __restrict__ comb,
    const float* __restrict__ combB, const float* __restrict__ W_ht,
    const float* __restrict__ WeW, float* __restrict__ scores)
{
    __shared__ float AtT[32][68];
    __shared__ float Bt[32][132];
    __shared__ float wht_s[128];
    __shared__ float we_s[128];
    __shared__ float sred[64];
    const int t = threadIdx.x;
    const int row0 = blockIdx.x * 64;
    const int j0 = blockIdx.y * 128, k = blockIdx.z;
    const int b = row0 >> 9, s0 = row0 & 511;
    const float* B = comb + (long)k * HH;
    const int r4 = (t >> 4) * 4, c8 = (t & 15) * 8;
    if (t < 128) {
        wht_s[t] = W_ht[((k << 5) + b) * NH + j0 + t] + combB[k * NH + j0 + t];
        we_s[t]  = WeW[k * NH + j0 + t];
    }
    if (t < 64) sred[t] = 0.f;
    float acc[4][8];
    #pragma unroll
    for (int rr = 0; rr < 4; ++rr)
        #pragma unroll
        for (int cc = 0; cc < 8; ++cc) acc[rr][cc] = 0.f;
    for (int h0 = 0; h0 < NH; h0 += 32) {
        #pragma unroll
        for (int p = 0; p < 8; ++p) {
            int idx = p * 256 + t;
            int r = idx >> 5, hh = idx & 31;
            AtT[hh][r] = text[(long)(row0 + r) * NH + h0 + hh];
        }
        #pragma unroll
        for (int p = 0; p < 16; ++p) {
            int idx = p * 256 + t;
            int hh = idx >> 7, c = idx & 127;
            Bt[hh][c] = B[(long)(h0 + hh) * NH + j0 + c];
        }
        __syncthreads();
        for (int hh = 0; hh < 32; ++hh) {
            float4 av  = *(const float4*)&AtT[hh][r4];
            float4 bv0 = *(const float4*)&Bt[hh][c8];
            float4 bv1 = *(const float4*)&Bt[hh][c8 + 4];
            float a[4] = {av.x, av.y, av.z, av.w};
            float bb[8] = {bv0.x, bv0.y, bv0.z, bv0.w, bv1.x, bv1.y, bv1.z, bv1.w};
            #pragma unroll
            for (int rr = 0; rr < 4; ++rr)
                #pragma unroll
                for (int cc = 0; cc < 8; ++cc) acc[rr][cc] += a[rr] * bb[cc];
        }
        __syncthreads();
    }
    float part[4] = {0.f, 0.f, 0.f, 0.f};
    #pragma unroll
    for (int rr = 0; rr < 4; ++rr)
        #pragma unroll
        for (int cc = 0; cc < 8; ++cc)
            part[rr] += tanhf(acc[rr][cc] + wht_s[c8 + cc]) * we_s[c8 + cc];
    #pragma unroll
    for (int rr = 0; rr < 4; ++rr)
        atomicAdd(&sred[r4 + rr], part[rr]);
    __syncthreads();
    if (t < 64)
        atomicAdd(&scores[(((k << 5) + b) << 9) + s0 + t], sred[t]);
}

__global__ void softmax_kernel(const float* __restrict__ scores,
                               const float* __restrict__ headw_W, const float* __restrict__ headw_b,
                               const float* __restrict__ text,
                               const float* __restrict__ q_f32,
                               float* __restrict__ xT, float* __restrict__ out_prob, int hop)
{
    __shared__ float sc[NK][NS];
    __shared__ float red[256];
    __shared__ float rv[256];
    __shared__ int   ri[256];
    int b = blockIdx.x, t = threadIdx.x;
    for (int i = t; i < NK * NS; i += 256) {
        int k = i >> 9, s = i & 511;
        sc[k][s] = scores[((k*NB + b) << 9) + s];
    }
    __syncthreads();
    float fac[NK];
    for (int k = 0; k < NK; ++k) {
        float v0 = sc[k][t], v1 = sc[k][t + 256];
        red[t] = fmaxf(v0, v1);
        __syncthreads();
        for (int o = 128; o > 0; o >>= 1) { if (t < o) red[t] = fmaxf(red[t], red[t + o]); __syncthreads(); }
        float mx = red[0];
        __syncthreads();
        float e0 = expf(v0 - mx), e1 = expf(v1 - mx);
        sc[k][t] = e0; sc[k][t + 256] = e1;
        red[t] = e0 + e1;
        __syncthreads();
        for (int o = 128; o > 0; o >>= 1) { if (t < o) red[t] += red[t + o]; __syncthreads(); }
        fac[k] = headw_W[k] / red[0];
        __syncthreads();
    }
    float hwb = headw_b[0];
    float a0 = hwb, a1 = hwb;
    for (int k = 0; k < NK; ++k) { a0 += sc[k][t] * fac[k]; a1 += sc[k][t + 256] * fac[k]; }
    red[t] = a0*a0 + a1*a1;
    float bv; int bi;
    if (a0 >= a1) { bv = a0; bi = t; } else { bv = a1; bi = t + 256; }
    rv[t] = bv; ri[t] = bi;
    __syncthreads();
    for (int o = 128; o > 0; o >>= 1) {
        if (t < o) {
            red[t] += red[t + o];
            if (rv[t + o] > rv[t] || (rv[t + o] == rv[t] && ri[t + o] < ri[t])) { rv[t] = rv[t + o]; ri[t] = ri[t + o]; }
        }
        __syncthreads();
    }
    float scale = sqrtf(red[0]);
    int idx = ri[0];
    if (hop == 0) {
        out_prob[(b << 9) + t]       = a0 / scale;
        out_prob[(b << 9) + t + 256] = a1 / scale;
    }
    const float* trow = text + (long)(b * NS + idx) * NH;
    for (int i = t; i < NH; i += 256) {
        xT[i * NB + b]        = q_f32[b*NH + i];
        xT[(NH + i) * NB + b] = trow[i];
    }
}

// GRU matvec partials: grid (36 j-tiles, 3 c-groups); atomicAdd into sx/sh.
__global__ __launch_bounds__(256) void gru_mm3_kernel(
    const float* __restrict__ Wih, const float* __restrict__ Whh,
    const float* __restrict__ xT, const float* __restrict__ hT,
    float* __restrict__ sx, float* __restrict__ sh)
{
    __shared__ float xs[8192];
    int t = threadIdx.x;
    int tj = t & 63, tq = t >> 6;
    int j = blockIdx.x * 64 + tj;
    int cg = blockIdx.y;
    float acc[8];
    #pragma unroll
    for (int bq = 0; bq < 8; ++bq) acc[bq] = 0.f;
    for (int c = cg * 2; c < cg * 2 + 2; ++c) {
        for (int idx = t; idx < 8192; idx += 256) xs[idx] = xT[c * 8192 + idx];
        __syncthreads();
        #pragma unroll 8
        for (int ii = 0; ii < 256; ++ii) {
            float w = Wih[(long)(c * 256 + ii) * H3 + j];
            #pragma unroll
            for (int bq = 0; bq < 8; ++bq) acc[bq] += xs[ii * 32 + tq * 8 + bq] * w;
        }
        __syncthreads();
    }
    #pragma unroll
    for (int bq = 0; bq < 8; ++bq)
        atomicAdd(&sx[(long)(tq * 8 + bq) * H3 + j], acc[bq]);
    #pragma unroll
    for (int bq = 0; bq < 8; ++bq) acc[bq] = 0.f;
    {
        int c = cg;
        for (int idx = t; idx < 8192; idx += 256) xs[idx] = hT[c * 8192 + idx];
        __syncthreads();
        #pragma unroll 8
        for (int ii = 0; ii < 256; ++ii) {
            float w = Whh[(long)(c * 256 + ii) * H3 + j];
            #pragma unroll
            for (int bq = 0; bq < 8; ++bq) acc[bq] += xs[ii * 32 + tq * 8 + bq] * w;
        }
    }
    #pragma unroll
    for (int bq = 0; bq < 8; ++bq)
        atomicAdd(&sh[(long)(tq * 8 + bq) * H3 + j], acc[bq]);
}

__global__ void gate_kernel(const float* __restrict__ sx, const float* __restrict__ sh,
                            const float* __restrict__ bih, const float* __restrict__ bhh,
                            float* __restrict__ hT, float* __restrict__ q_f32,
                            float* __restrict__ out_h, int hop)
{
    int gid = blockIdx.x * 256 + threadIdx.x;
    int b = gid / NH, j = gid % NH;
    float xr = bih[j]        + sx[b*H3 + j];
    float xz = bih[NH + j]   + sx[b*H3 + NH + j];
    float xn = bih[1536 + j] + sx[b*H3 + 1536 + j];
    float hr = bhh[j]        + sh[b*H3 + j];
    float hz = bhh[NH + j]   + sh[b*H3 + NH + j];
    float hn = bhh[1536 + j] + sh[b*H3 + 1536 + j];
    float r = 1.f / (1.f + expf(-(xr + hr)));
    float z = 1.f / (1.f + expf(-(xz + hz)));
    float n = tanhf(xn + r * hn);
    float hp = hT[j * NB + b];
    float hnew = (1.f - z) * n + z * hp;
    hT[j * NB + b] = hnew;
    q_f32[gid] = hnew;
    out_h[(long)(b * 3 + hop) * NH + j] = hnew;
}

// ---------------------------------------------------------------------------
extern "C" void kernel_launch(void* const* d_in, const int* in_sizes, int n_in,
                              void* d_out, int out_size, void* d_ws, size_t ws_size,
                              hipStream_t stream)
{
    const float* question = (const float*)d_in[0];
    const float* text     = (const float*)d_in[1];
    const float* pw_W     = (const float*)d_in[2];
    const float* pw_b     = (const float*)d_in[3];
    const float* Ws_W     = (const float*)d_in[4];
    const float* Ws_b     = (const float*)d_in[5];
    const float* Wt_W     = (const float*)d_in[6];
    const float* Wt_b     = (const float*)d_in[7];
    const float* We_W     = (const float*)d_in[8];
    const float* We_b     = (const float*)d_in[9];
    const float* headw_W  = (const float*)d_in[10];
    const float* headw_b  = (const float*)d_in[11];
    const float* Wih      = (const float*)d_in[12];
    const float* Whh      = (const float*)d_in[13];
    const float* bih      = (const float*)d_in[14];
    const float* bhh      = (const float*)d_in[15];

    char* ws = (char*)d_ws;
    float* comb   = (float*)(ws + 0);
    float* combB  = (float*)(ws + 9437184);
    float* W_ht   = (float*)(ws + 9449472);
    float* scores = (float*)(ws + 9842688);
    float* q_f32  = (float*)(ws + 10104832);
    float* hT     = (float*)(ws + 10203136);
    float* xT     = (float*)(ws + 10301440);
    float* sx     = (float*)(ws + 10498048);
    float* sh     = (float*)(ws + 10792960);
    u16*   combTH = (u16*)  (ws + 11087872);
    u16*   combTL = (u16*)  (ws + 15806464);
    u16*   textH  = (u16*)  (ws + 20525056);
    u16*   textL  = (u16*)  (ws + 45690880);
    // tier2 prep scratch overlaid on textH region (dead before split_text):
    u16*   WsTH   = (u16*)  (ws + 20525056);
    u16*   WsTL   = (u16*)  (ws + 25243648);
    u16*   pwH    = (u16*)  (ws + 29962240);
    u16*   pwL    = (u16*)  (ws + 34680832);
    const int tier = (ws_size >= (size_t)70856704) ? 2
                   : (ws_size >= (size_t)20525056) ? 1 : 0;

    float* out_prob = (float*)d_out;
    float* out_h    = (float*)d_out + NB * NS;

    prep_kernel<<<4848, 256, 0, stream>>>(Ws_W, pw_b, Ws_b, combB, question, q_f32, hT,
                                          pw_W, WsTH, WsTL, pwH, pwL, tier);
    if (tier == 2) {
        comb_mfma_kernel<<<dim3(6, 6, 4), 256, 0, stream>>>(WsTH, WsTL, pwH, pwL,
                                                            combTH, combTL);
        split_text_kernel<<<12288, 256, 0, stream>>>(text, textH, textL);
    } else {
        comb_valu_kernel<<<dim3(12, 6, 4), 256, 0, stream>>>(pw_W, Ws_W, comb);
        if (tier == 1)
            split_combT_kernel<<<2304, 256, 0, stream>>>(comb, combTH, combTL);
    }

    for (int hop = 0; hop < 3; ++hop) {
        init_hop_kernel<<<1216, 256, 0, stream>>>(We_b, scores, Wt_b, W_ht, sx, sh);
        wht2_kernel<<<1536, 256, 0, stream>>>(q_f32, Wt_W, W_ht);
        if (tier == 2) {
            fused_scores_mfma<1><<<dim3(128, 6, 4), 256, 0, stream>>>(
                text, textH, textL, combTH, combTL, combB, W_ht, We_W, scores);
        } else if (tier == 1) {
            fused_scores_mfma<0><<<dim3(128, 6, 4), 256, 0, stream>>>(
                text, nullptr, nullptr, combTH, combTL, combB, W_ht, We_W, scores);
        } else {
            fused_scores_valu<<<dim3(256, 6, 4), 256, 0, stream>>>(
                text, comb, combB, W_ht, We_W, scores);
        }
        softmax_kernel<<<32, 256, 0, stream>>>(scores, headw_W, headw_b, text,
                                               q_f32, xT, out_prob, hop);
        gru_mm3_kernel<<<dim3(36, 3), 256, 0, stream>>>(Wih, Whh, xT, hT, sx, sh);
        gate_kernel<<<96, 256, 0, stream>>>(sx, sh, bih, bhh, hT, q_f32, out_h, hop);
    }
}